// Round 8
// baseline (371.765 us; speedup 1.0000x reference)
//
#include <hip/hip_runtime.h>
#include <math.h>

#define N_ENT 4096
#define BATCH 4
#define NHID  3
#define EMB   64
#define ALPHA 0.2f
#define MASK_FILL 9e-15f
#define LOG2E 1.4426950408889634f
#define MASKP (MASK_FILL * LOG2E)

#if defined(__has_builtin)
#  if __has_builtin(__builtin_amdgcn_exp2f)
#    define EXP2F(x) __builtin_amdgcn_exp2f(x)
#  else
#    define EXP2F(x) exp2f(x)
#  endif
#else
#  define EXP2F(x) exp2f(x)
#endif

typedef int v4i __attribute__((ext_vector_type(4)));

// nontemporal 16B adjacency load: no-allocate (R7: +23us vs cached loads —
// avoids dirty-victim coupling with the harness's 1GB ws poison).
__device__ __forceinline__ v4i nt_load(const v4i* p) {
    return __builtin_nontemporal_load(p);
}

// ---------------------------------------------------------------------------
// Kernel 1: h = ent_emb @ W; dst' = (h@a[3:])*log2e; src' = (h@a[:3])*log2e.
// ---------------------------------------------------------------------------
__global__ __launch_bounds__(256) void prep_kernel(
    const float* __restrict__ emb, const float* __restrict__ W,
    const float* __restrict__ a,
    float* __restrict__ h0G, float* __restrict__ h1G, float* __restrict__ h2G,
    float* __restrict__ dstG, float* __restrict__ srcG)
{
    int j = blockIdx.x * 256 + threadIdx.x;
    if (j >= N_ENT) return;
    const float* er = emb + (size_t)j * EMB;
    float h0 = 0.f, h1 = 0.f, h2 = 0.f;
    #pragma unroll
    for (int e = 0; e < EMB; ++e) {
        float v = er[e];
        h0 += v * W[e * 3 + 0];
        h1 += v * W[e * 3 + 1];
        h2 += v * W[e * 3 + 2];
    }
    h0G[j] = h0; h1G[j] = h1; h2G[j] = h2;
    srcG[j] = (h0 * a[0] + h1 * a[1] + h2 * a[2]) * LOG2E;
    dstG[j] = (h0 * a[3] + h1 * a[4] + h2 * a[5]) * LOG2E;
}

// ---------------------------------------------------------------------------
// Kernel 2: one wave per entity i, all four batch rows together.
// R8 changes vs R7 (structure only, same math):
//  - FULLY UNROLLED 16-chunk loop, depth-4 rotating register buffers:
//    prefetch emitted only for c<12 (compile-time) -> no phantom wrap loads
//    (R7 wasted 12.5% of adj reads), 4-iter lookahead covers ~900cy latency.
//  - grid 512 x 512 threads (8 entities/block): 64KB LDS -> 2 co-resident
//    blocks/CU (R7 had exactly 1 block/CU: zero inter-block overlap).
// Fixed-reference softmax: M = max(lrelu(src+maxd), MASKP) >= all logits
// (lrelu monotone, maxd = global max of dst) -> exact, no overflow.
// ---------------------------------------------------------------------------
__global__ __launch_bounds__(512, 4) void gat_row_kernel(
    const int* __restrict__ adj,
    const float* __restrict__ h0G, const float* __restrict__ h1G,
    const float* __restrict__ h2G, const float* __restrict__ dstG,
    const float* __restrict__ srcG, float* __restrict__ xG)
{
    __shared__ float dstL[N_ENT];   // SoA
    __shared__ float h0L[N_ENT];
    __shared__ float h1L[N_ENT];
    __shared__ float h2L[N_ENT];
    __shared__ float maxdL[8];

    int tid  = threadIdx.x;
    int lane = tid & 63;
    int wid  = tid >> 6;            // 0..7

    float md = -3.4e38f;
    #pragma unroll
    for (int t = tid; t < N_ENT; t += 512) {
        float dv = dstG[t];
        dstL[t] = dv;
        md = fmaxf(md, dv);
        h0L[t] = h0G[t];
        h1L[t] = h1G[t];
        h2L[t] = h2G[t];
    }
    #pragma unroll
    for (int off = 32; off; off >>= 1) md = fmaxf(md, __shfl_xor(md, off, 64));
    if (lane == 0) maxdL[wid] = md;
    __syncthreads();
    float maxd = maxdL[0];
    #pragma unroll
    for (int t = 1; t < 8; ++t) maxd = fmaxf(maxd, maxdL[t]);

    int i = blockIdx.x * 8 + wid;         // entity index, 0..4095

    float srcp = srcG[i];                 // scaled by log2e
    float tt = srcp + maxd;
    float M  = fmaxf(fmaxf(tt, ALPHA * tt), (float)MASKP);
    float s0 = srcp - M, s1 = ALPHA * srcp - M;
    float C  = EXP2F((float)MASKP - M);   // shared non-edge weight

    const v4i* p0 = (const v4i*)(adj + ((size_t)0 * N_ENT + i) * N_ENT);
    const v4i* p1 = (const v4i*)(adj + ((size_t)1 * N_ENT + i) * N_ENT);
    const v4i* p2 = (const v4i*)(adj + ((size_t)2 * N_ENT + i) * N_ENT);
    const v4i* p3 = (const v4i*)(adj + ((size_t)3 * N_ENT + i) * N_ENT);

    // depth-4 rotating buffers, 4 batch streams (full unroll -> registers)
    v4i bA[4], bB[4], bC[4], bD[4];
    #pragma unroll
    for (int c = 0; c < 4; ++c) {
        bA[c] = nt_load(p0 + c * 64 + lane);
        bB[c] = nt_load(p1 + c * 64 + lane);
        bC[c] = nt_load(p2 + c * 64 + lane);
        bD[c] = nt_load(p3 + c * 64 + lane);
    }

    float l0 = 0.f, n00 = 0.f, n01 = 0.f, n02 = 0.f;
    float l1 = 0.f, n10 = 0.f, n11 = 0.f, n12 = 0.f;
    float l2 = 0.f, n20 = 0.f, n21 = 0.f, n22 = 0.f;
    float l3 = 0.f, n30 = 0.f, n31 = 0.f, n32 = 0.f;

    #pragma unroll
    for (int c = 0; c < 16; ++c) {
        int s = c & 3;
        v4i a0v = bA[s], a1v = bB[s], a2v = bC[s], a3v = bD[s];
        if (c < 12) {                     // compile-time after full unroll
            int cn = c + 4;
            bA[s] = nt_load(p0 + cn * 64 + lane);
            bB[s] = nt_load(p1 + cn * 64 + lane);
            bC[s] = nt_load(p2 + cn * 64 + lane);
            bD[s] = nt_load(p3 + cn * 64 + lane);
        }

        int jb = (c * 64 + lane) * 4;
        float4 d4 = *(const float4*)&dstL[jb];
        float4 h0 = *(const float4*)&h0L[jb];
        float4 h1 = *(const float4*)&h1L[jb];
        float4 h2 = *(const float4*)&h2L[jb];

        // shared exponentials (same for all 4 batches)
        float g0 = EXP2F(fmaxf(s0 + d4.x, fmaf(ALPHA, d4.x, s1)));
        float g1 = EXP2F(fmaxf(s0 + d4.y, fmaf(ALPHA, d4.y, s1)));
        float g2 = EXP2F(fmaxf(s0 + d4.z, fmaf(ALPHA, d4.z, s1)));
        float g3 = EXP2F(fmaxf(s0 + d4.w, fmaf(ALPHA, d4.w, s1)));

        {   // batch 0
            float w0 = a0v.x > 0 ? g0 : C, w1 = a0v.y > 0 ? g1 : C;
            float w2 = a0v.z > 0 ? g2 : C, w3 = a0v.w > 0 ? g3 : C;
            l0 += (w0 + w1) + (w2 + w3);
            n00 = fmaf(w0, h0.x, fmaf(w1, h0.y, fmaf(w2, h0.z, fmaf(w3, h0.w, n00))));
            n01 = fmaf(w0, h1.x, fmaf(w1, h1.y, fmaf(w2, h1.z, fmaf(w3, h1.w, n01))));
            n02 = fmaf(w0, h2.x, fmaf(w1, h2.y, fmaf(w2, h2.z, fmaf(w3, h2.w, n02))));
        }
        {   // batch 1
            float w0 = a1v.x > 0 ? g0 : C, w1 = a1v.y > 0 ? g1 : C;
            float w2 = a1v.z > 0 ? g2 : C, w3 = a1v.w > 0 ? g3 : C;
            l1 += (w0 + w1) + (w2 + w3);
            n10 = fmaf(w0, h0.x, fmaf(w1, h0.y, fmaf(w2, h0.z, fmaf(w3, h0.w, n10))));
            n11 = fmaf(w0, h1.x, fmaf(w1, h1.y, fmaf(w2, h1.z, fmaf(w3, h1.w, n11))));
            n12 = fmaf(w0, h2.x, fmaf(w1, h2.y, fmaf(w2, h2.z, fmaf(w3, h2.w, n12))));
        }
        {   // batch 2
            float w0 = a2v.x > 0 ? g0 : C, w1 = a2v.y > 0 ? g1 : C;
            float w2 = a2v.z > 0 ? g2 : C, w3 = a2v.w > 0 ? g3 : C;
            l2 += (w0 + w1) + (w2 + w3);
            n20 = fmaf(w0, h0.x, fmaf(w1, h0.y, fmaf(w2, h0.z, fmaf(w3, h0.w, n20))));
            n21 = fmaf(w0, h1.x, fmaf(w1, h1.y, fmaf(w2, h1.z, fmaf(w3, h1.w, n21))));
            n22 = fmaf(w0, h2.x, fmaf(w1, h2.y, fmaf(w2, h2.z, fmaf(w3, h2.w, n22))));
        }
        {   // batch 3
            float w0 = a3v.x > 0 ? g0 : C, w1 = a3v.y > 0 ? g1 : C;
            float w2 = a3v.z > 0 ? g2 : C, w3 = a3v.w > 0 ? g3 : C;
            l3 += (w0 + w1) + (w2 + w3);
            n30 = fmaf(w0, h0.x, fmaf(w1, h0.y, fmaf(w2, h0.z, fmaf(w3, h0.w, n30))));
            n31 = fmaf(w0, h1.x, fmaf(w1, h1.y, fmaf(w2, h1.z, fmaf(w3, h1.w, n31))));
            n32 = fmaf(w0, h2.x, fmaf(w1, h2.y, fmaf(w2, h2.z, fmaf(w3, h2.w, n32))));
        }
    }

    #pragma unroll
    for (int off = 32; off; off >>= 1) {
        l0  += __shfl_xor(l0,  off, 64);
        n00 += __shfl_xor(n00, off, 64);
        n01 += __shfl_xor(n01, off, 64);
        n02 += __shfl_xor(n02, off, 64);
        l1  += __shfl_xor(l1,  off, 64);
        n10 += __shfl_xor(n10, off, 64);
        n11 += __shfl_xor(n11, off, 64);
        n12 += __shfl_xor(n12, off, 64);
        l2  += __shfl_xor(l2,  off, 64);
        n20 += __shfl_xor(n20, off, 64);
        n21 += __shfl_xor(n21, off, 64);
        n22 += __shfl_xor(n22, off, 64);
        l3  += __shfl_xor(l3,  off, 64);
        n30 += __shfl_xor(n30, off, 64);
        n31 += __shfl_xor(n31, off, 64);
        n32 += __shfl_xor(n32, off, 64);
    }

    if (lane == 0) {
        float inv, v0, v1, v2;
        float* xp;
        inv = 1.f / l0; v0 = n00*inv; v1 = n01*inv; v2 = n02*inv;
        xp = xG + ((size_t)0 * N_ENT + i) * 3;
        xp[0] = v0 > 0.f ? v0 : expm1f(v0);
        xp[1] = v1 > 0.f ? v1 : expm1f(v1);
        xp[2] = v2 > 0.f ? v2 : expm1f(v2);
        inv = 1.f / l1; v0 = n10*inv; v1 = n11*inv; v2 = n12*inv;
        xp = xG + ((size_t)1 * N_ENT + i) * 3;
        xp[0] = v0 > 0.f ? v0 : expm1f(v0);
        xp[1] = v1 > 0.f ? v1 : expm1f(v1);
        xp[2] = v2 > 0.f ? v2 : expm1f(v2);
        inv = 1.f / l2; v0 = n20*inv; v1 = n21*inv; v2 = n22*inv;
        xp = xG + ((size_t)2 * N_ENT + i) * 3;
        xp[0] = v0 > 0.f ? v0 : expm1f(v0);
        xp[1] = v1 > 0.f ? v1 : expm1f(v1);
        xp[2] = v2 > 0.f ? v2 : expm1f(v2);
        inv = 1.f / l3; v0 = n30*inv; v1 = n31*inv; v2 = n32*inv;
        xp = xG + ((size_t)3 * N_ENT + i) * 3;
        xp[0] = v0 > 0.f ? v0 : expm1f(v0);
        xp[1] = v1 > 0.f ? v1 : expm1f(v1);
        xp[2] = v2 > 0.f ? v2 : expm1f(v2);
    }
}

// ---------------------------------------------------------------------------
// Kernel 3: out[b,k] = x[b,:] . fc1_w[k,:] + fc1_b[k].
// ---------------------------------------------------------------------------
__global__ __launch_bounds__(256) void fc_kernel(
    const float* __restrict__ xG, const float* __restrict__ w,
    const float* __restrict__ bias, float* __restrict__ out)
{
    int k   = blockIdx.x;           // 0..99
    int tid = threadIdx.x;
    const float4* wr = (const float4*)(w + (size_t)k * (N_ENT * NHID));
    const float4* x0 = (const float4*)(xG + 0 * (N_ENT * NHID));
    const float4* x1 = (const float4*)(xG + 1 * (N_ENT * NHID));
    const float4* x2 = (const float4*)(xG + 2 * (N_ENT * NHID));
    const float4* x3 = (const float4*)(xG + 3 * (N_ENT * NHID));

    float acc0 = 0.f, acc1 = 0.f, acc2 = 0.f, acc3 = 0.f;
    for (int t = tid; t < (N_ENT * NHID / 4); t += 256) {
        float4 wv = wr[t];
        float4 xv;
        xv = x0[t]; acc0 += wv.x*xv.x + wv.y*xv.y + wv.z*xv.z + wv.w*xv.w;
        xv = x1[t]; acc1 += wv.x*xv.x + wv.y*xv.y + wv.z*xv.z + wv.w*xv.w;
        xv = x2[t]; acc2 += wv.x*xv.x + wv.y*xv.y + wv.z*xv.z + wv.w*xv.w;
        xv = x3[t]; acc3 += wv.x*xv.x + wv.y*xv.y + wv.z*xv.z + wv.w*xv.w;
    }

    #pragma unroll
    for (int off = 32; off; off >>= 1) {
        acc0 += __shfl_xor(acc0, off, 64);
        acc1 += __shfl_xor(acc1, off, 64);
        acc2 += __shfl_xor(acc2, off, 64);
        acc3 += __shfl_xor(acc3, off, 64);
    }

    __shared__ float red[4][4];
    int lane = tid & 63, wv_ = tid >> 6;
    if (lane == 0) {
        red[wv_][0] = acc0; red[wv_][1] = acc1;
        red[wv_][2] = acc2; red[wv_][3] = acc3;
    }
    __syncthreads();
    if (tid < 4) {
        float s = red[0][tid] + red[1][tid] + red[2][tid] + red[3][tid] + bias[k];
        out[tid * 100 + k] = s;
    }
}

// ---------------------------------------------------------------------------
extern "C" void kernel_launch(void* const* d_in, const int* in_sizes, int n_in,
                              void* d_out, int out_size, void* d_ws, size_t ws_size,
                              hipStream_t stream)
{
    const int*   adj  = (const int*)d_in[0];
    const float* emb  = (const float*)d_in[1];
    const float* W    = (const float*)d_in[2];
    const float* a    = (const float*)d_in[3];
    const float* fc1w = (const float*)d_in[4];
    const float* fc1b = (const float*)d_in[5];
    float* out = (float*)d_out;

    float* ws   = (float*)d_ws;
    float* h0G  = ws;               // 4096
    float* h1G  = ws + 4096;        // 4096
    float* h2G  = ws + 8192;        // 4096
    float* dstG = ws + 12288;       // 4096
    float* srcG = ws + 16384;       // 4096
    float* xG   = ws + 20480;       // 4*4096*3 = 49152

    prep_kernel<<<N_ENT / 256, 256, 0, stream>>>(emb, W, a, h0G, h1G, h2G, dstG, srcG);
    gat_row_kernel<<<N_ENT / 8, 512, 0, stream>>>(adj, h0G, h1G, h2G, dstG, srcG, xG);
    fc_kernel<<<100, 256, 0, stream>>>(xG, fc1w, fc1b, out);
}

// Round 9
// 360.281 us; speedup vs baseline: 1.0319x; 1.0319x over previous
//
#include <hip/hip_runtime.h>
#include <math.h>

#define N_ENT 4096
#define BATCH 4
#define NHID  3
#define EMB   64
#define ALPHA 0.2f
#define MASK_FILL 9e-15f
#define LOG2E 1.4426950408889634f
#define MASKP (MASK_FILL * LOG2E)

#if defined(__has_builtin)
#  if __has_builtin(__builtin_amdgcn_exp2f)
#    define EXP2F(x) __builtin_amdgcn_exp2f(x)
#  else
#    define EXP2F(x) exp2f(x)
#  endif
#else
#  define EXP2F(x) exp2f(x)
#endif

typedef int v4i __attribute__((ext_vector_type(4)));

// nontemporal 16B adjacency load: no-allocate (R7: +23us vs cached loads —
// avoids dirty-victim coupling with the harness's 1GB ws poison).
__device__ __forceinline__ v4i nt_load(const v4i* p) {
    return __builtin_nontemporal_load(p);
}

// ---------------------------------------------------------------------------
// Kernel 1: h = ent_emb @ W; dst' = (h@a[3:])*log2e; src' = (h@a[:3])*log2e.
// ---------------------------------------------------------------------------
__global__ __launch_bounds__(256) void prep_kernel(
    const float* __restrict__ emb, const float* __restrict__ W,
    const float* __restrict__ a,
    float* __restrict__ h0G, float* __restrict__ h1G, float* __restrict__ h2G,
    float* __restrict__ dstG, float* __restrict__ srcG)
{
    int j = blockIdx.x * 256 + threadIdx.x;
    if (j >= N_ENT) return;
    const float* er = emb + (size_t)j * EMB;
    float h0 = 0.f, h1 = 0.f, h2 = 0.f;
    #pragma unroll
    for (int e = 0; e < EMB; ++e) {
        float v = er[e];
        h0 += v * W[e * 3 + 0];
        h1 += v * W[e * 3 + 1];
        h2 += v * W[e * 3 + 2];
    }
    h0G[j] = h0; h1G[j] = h1; h2G[j] = h2;
    srcG[j] = (h0 * a[0] + h1 * a[1] + h2 * a[2]) * LOG2E;
    dstG[j] = (h0 * a[3] + h1 * a[4] + h2 * a[5]) * LOG2E;
}

// ---------------------------------------------------------------------------
// Kernel 2: R7 structure (one wave per entity, 4 batch rows share exp2/LDS,
// depth-2 NT prefetch, 1024 threads, 16 waves/CU) with ONE change:
// the last two loop iterations are PEELED so the prefetch index c+2 is always
// valid — removes R7's 8 phantom wrap loads/wave (33.5 MB = 12.5% extra HBM).
// Fixed-reference softmax: M = max(lrelu(src+maxd), MASKP) >= all logits.
// ---------------------------------------------------------------------------
#define GAT_BODY(cc, A0, A1, A2, A3)                                          \
    do {                                                                      \
        int jb = ((cc) * 64 + lane) * 4;                                      \
        float4 d4 = *(const float4*)&dstL[jb];                                \
        float4 h0 = *(const float4*)&h0L[jb];                                 \
        float4 h1 = *(const float4*)&h1L[jb];                                 \
        float4 h2 = *(const float4*)&h2L[jb];                                 \
        float g0 = EXP2F(fmaxf(s0 + d4.x, fmaf(ALPHA, d4.x, s1)));            \
        float g1 = EXP2F(fmaxf(s0 + d4.y, fmaf(ALPHA, d4.y, s1)));            \
        float g2 = EXP2F(fmaxf(s0 + d4.z, fmaf(ALPHA, d4.z, s1)));            \
        float g3 = EXP2F(fmaxf(s0 + d4.w, fmaf(ALPHA, d4.w, s1)));            \
        {                                                                     \
            float w0 = (A0).x > 0 ? g0 : C, w1 = (A0).y > 0 ? g1 : C;         \
            float w2 = (A0).z > 0 ? g2 : C, w3 = (A0).w > 0 ? g3 : C;         \
            l0 += (w0 + w1) + (w2 + w3);                                      \
            n00 = fmaf(w0, h0.x, fmaf(w1, h0.y, fmaf(w2, h0.z, fmaf(w3, h0.w, n00)))); \
            n01 = fmaf(w0, h1.x, fmaf(w1, h1.y, fmaf(w2, h1.z, fmaf(w3, h1.w, n01)))); \
            n02 = fmaf(w0, h2.x, fmaf(w1, h2.y, fmaf(w2, h2.z, fmaf(w3, h2.w, n02)))); \
        }                                                                     \
        {                                                                     \
            float w0 = (A1).x > 0 ? g0 : C, w1 = (A1).y > 0 ? g1 : C;         \
            float w2 = (A1).z > 0 ? g2 : C, w3 = (A1).w > 0 ? g3 : C;         \
            l1 += (w0 + w1) + (w2 + w3);                                      \
            n10 = fmaf(w0, h0.x, fmaf(w1, h0.y, fmaf(w2, h0.z, fmaf(w3, h0.w, n10)))); \
            n11 = fmaf(w0, h1.x, fmaf(w1, h1.y, fmaf(w2, h1.z, fmaf(w3, h1.w, n11)))); \
            n12 = fmaf(w0, h2.x, fmaf(w1, h2.y, fmaf(w2, h2.z, fmaf(w3, h2.w, n12)))); \
        }                                                                     \
        {                                                                     \
            float w0 = (A2).x > 0 ? g0 : C, w1 = (A2).y > 0 ? g1 : C;         \
            float w2 = (A2).z > 0 ? g2 : C, w3 = (A2).w > 0 ? g3 : C;         \
            l2 += (w0 + w1) + (w2 + w3);                                      \
            n20 = fmaf(w0, h0.x, fmaf(w1, h0.y, fmaf(w2, h0.z, fmaf(w3, h0.w, n20)))); \
            n21 = fmaf(w0, h1.x, fmaf(w1, h1.y, fmaf(w2, h1.z, fmaf(w3, h1.w, n21)))); \
            n22 = fmaf(w0, h2.x, fmaf(w1, h2.y, fmaf(w2, h2.z, fmaf(w3, h2.w, n22)))); \
        }                                                                     \
        {                                                                     \
            float w0 = (A3).x > 0 ? g0 : C, w1 = (A3).y > 0 ? g1 : C;         \
            float w2 = (A3).z > 0 ? g2 : C, w3 = (A3).w > 0 ? g3 : C;         \
            l3 += (w0 + w1) + (w2 + w3);                                      \
            n30 = fmaf(w0, h0.x, fmaf(w1, h0.y, fmaf(w2, h0.z, fmaf(w3, h0.w, n30)))); \
            n31 = fmaf(w0, h1.x, fmaf(w1, h1.y, fmaf(w2, h1.z, fmaf(w3, h1.w, n31)))); \
            n32 = fmaf(w0, h2.x, fmaf(w1, h2.y, fmaf(w2, h2.z, fmaf(w3, h2.w, n32)))); \
        }                                                                     \
    } while (0)

__global__ __launch_bounds__(1024, 4) void gat_row_kernel(
    const int* __restrict__ adj,
    const float* __restrict__ h0G, const float* __restrict__ h1G,
    const float* __restrict__ h2G, const float* __restrict__ dstG,
    const float* __restrict__ srcG, float* __restrict__ xG)
{
    __shared__ float dstL[N_ENT];   // SoA: b128 reads bank-clean
    __shared__ float h0L[N_ENT];
    __shared__ float h1L[N_ENT];
    __shared__ float h2L[N_ENT];
    __shared__ float maxdL[16];

    int tid  = threadIdx.x;
    int lane = tid & 63;
    int wid  = tid >> 6;            // 0..15

    float md = -3.4e38f;
    #pragma unroll
    for (int t = tid; t < N_ENT; t += 1024) {
        float dv = dstG[t];
        dstL[t] = dv;
        md = fmaxf(md, dv);
        h0L[t] = h0G[t];
        h1L[t] = h1G[t];
        h2L[t] = h2G[t];
    }
    #pragma unroll
    for (int off = 32; off; off >>= 1) md = fmaxf(md, __shfl_xor(md, off, 64));
    if (lane == 0) maxdL[wid] = md;
    __syncthreads();
    float maxd = maxdL[0];
    #pragma unroll
    for (int t = 1; t < 16; ++t) maxd = fmaxf(maxd, maxdL[t]);

    int i = blockIdx.x * 16 + wid;        // entity index, 0..4095

    float srcp = srcG[i];                 // scaled by log2e
    float tt = srcp + maxd;
    float M  = fmaxf(fmaxf(tt, ALPHA * tt), (float)MASKP);
    float s0 = srcp - M, s1 = ALPHA * srcp - M;
    float C  = EXP2F((float)MASKP - M);   // shared non-edge weight

    const v4i* p0 = (const v4i*)(adj + ((size_t)0 * N_ENT + i) * N_ENT);
    const v4i* p1 = (const v4i*)(adj + ((size_t)1 * N_ENT + i) * N_ENT);
    const v4i* p2 = (const v4i*)(adj + ((size_t)2 * N_ENT + i) * N_ENT);
    const v4i* p3 = (const v4i*)(adj + ((size_t)3 * N_ENT + i) * N_ENT);

    // depth-2 prefetch pipeline, 4 batch streams, nontemporal
    v4i cur0 = nt_load(p0 + lane),      cur1 = nt_load(p1 + lane);
    v4i cur2 = nt_load(p2 + lane),      cur3 = nt_load(p3 + lane);
    v4i nxt0 = nt_load(p0 + 64 + lane), nxt1 = nt_load(p1 + 64 + lane);
    v4i nxt2 = nt_load(p2 + 64 + lane), nxt3 = nt_load(p3 + 64 + lane);

    float l0 = 0.f, n00 = 0.f, n01 = 0.f, n02 = 0.f;
    float l1 = 0.f, n10 = 0.f, n11 = 0.f, n12 = 0.f;
    float l2 = 0.f, n20 = 0.f, n21 = 0.f, n22 = 0.f;
    float l3 = 0.f, n30 = 0.f, n31 = 0.f, n32 = 0.f;

    #pragma unroll 1
    for (int c = 0; c < 14; ++c) {        // prefetch c+2 always valid
        v4i a0v = cur0, a1v = cur1, a2v = cur2, a3v = cur3;
        cur0 = nxt0; cur1 = nxt1; cur2 = nxt2; cur3 = nxt3;
        int cn = c + 2;
        nxt0 = nt_load(p0 + cn * 64 + lane);
        nxt1 = nt_load(p1 + cn * 64 + lane);
        nxt2 = nt_load(p2 + cn * 64 + lane);
        nxt3 = nt_load(p3 + cn * 64 + lane);
        GAT_BODY(c, a0v, a1v, a2v, a3v);
    }
    // peeled tail: chunks 14 (cur) and 15 (nxt), no prefetch
    GAT_BODY(14, cur0, cur1, cur2, cur3);
    GAT_BODY(15, nxt0, nxt1, nxt2, nxt3);

    #pragma unroll
    for (int off = 32; off; off >>= 1) {
        l0  += __shfl_xor(l0,  off, 64);
        n00 += __shfl_xor(n00, off, 64);
        n01 += __shfl_xor(n01, off, 64);
        n02 += __shfl_xor(n02, off, 64);
        l1  += __shfl_xor(l1,  off, 64);
        n10 += __shfl_xor(n10, off, 64);
        n11 += __shfl_xor(n11, off, 64);
        n12 += __shfl_xor(n12, off, 64);
        l2  += __shfl_xor(l2,  off, 64);
        n20 += __shfl_xor(n20, off, 64);
        n21 += __shfl_xor(n21, off, 64);
        n22 += __shfl_xor(n22, off, 64);
        l3  += __shfl_xor(l3,  off, 64);
        n30 += __shfl_xor(n30, off, 64);
        n31 += __shfl_xor(n31, off, 64);
        n32 += __shfl_xor(n32, off, 64);
    }

    if (lane == 0) {
        float inv, v0, v1, v2;
        float* xp;
        inv = 1.f / l0; v0 = n00*inv; v1 = n01*inv; v2 = n02*inv;
        xp = xG + ((size_t)0 * N_ENT + i) * 3;
        xp[0] = v0 > 0.f ? v0 : expm1f(v0);
        xp[1] = v1 > 0.f ? v1 : expm1f(v1);
        xp[2] = v2 > 0.f ? v2 : expm1f(v2);
        inv = 1.f / l1; v0 = n10*inv; v1 = n11*inv; v2 = n12*inv;
        xp = xG + ((size_t)1 * N_ENT + i) * 3;
        xp[0] = v0 > 0.f ? v0 : expm1f(v0);
        xp[1] = v1 > 0.f ? v1 : expm1f(v1);
        xp[2] = v2 > 0.f ? v2 : expm1f(v2);
        inv = 1.f / l2; v0 = n20*inv; v1 = n21*inv; v2 = n22*inv;
        xp = xG + ((size_t)2 * N_ENT + i) * 3;
        xp[0] = v0 > 0.f ? v0 : expm1f(v0);
        xp[1] = v1 > 0.f ? v1 : expm1f(v1);
        xp[2] = v2 > 0.f ? v2 : expm1f(v2);
        inv = 1.f / l3; v0 = n30*inv; v1 = n31*inv; v2 = n32*inv;
        xp = xG + ((size_t)3 * N_ENT + i) * 3;
        xp[0] = v0 > 0.f ? v0 : expm1f(v0);
        xp[1] = v1 > 0.f ? v1 : expm1f(v1);
        xp[2] = v2 > 0.f ? v2 : expm1f(v2);
    }
}

// ---------------------------------------------------------------------------
// Kernel 3: out[b,k] = x[b,:] . fc1_w[k,:] + fc1_b[k].
// ---------------------------------------------------------------------------
__global__ __launch_bounds__(256) void fc_kernel(
    const float* __restrict__ xG, const float* __restrict__ w,
    const float* __restrict__ bias, float* __restrict__ out)
{
    int k   = blockIdx.x;           // 0..99
    int tid = threadIdx.x;
    const float4* wr = (const float4*)(w + (size_t)k * (N_ENT * NHID));
    const float4* x0 = (const float4*)(xG + 0 * (N_ENT * NHID));
    const float4* x1 = (const float4*)(xG + 1 * (N_ENT * NHID));
    const float4* x2 = (const float4*)(xG + 2 * (N_ENT * NHID));
    const float4* x3 = (const float4*)(xG + 3 * (N_ENT * NHID));

    float acc0 = 0.f, acc1 = 0.f, acc2 = 0.f, acc3 = 0.f;
    for (int t = tid; t < (N_ENT * NHID / 4); t += 256) {
        float4 wv = wr[t];
        float4 xv;
        xv = x0[t]; acc0 += wv.x*xv.x + wv.y*xv.y + wv.z*xv.z + wv.w*xv.w;
        xv = x1[t]; acc1 += wv.x*xv.x + wv.y*xv.y + wv.z*xv.z + wv.w*xv.w;
        xv = x2[t]; acc2 += wv.x*xv.x + wv.y*xv.y + wv.z*xv.z + wv.w*xv.w;
        xv = x3[t]; acc3 += wv.x*xv.x + wv.y*xv.y + wv.z*xv.z + wv.w*xv.w;
    }

    #pragma unroll
    for (int off = 32; off; off >>= 1) {
        acc0 += __shfl_xor(acc0, off, 64);
        acc1 += __shfl_xor(acc1, off, 64);
        acc2 += __shfl_xor(acc2, off, 64);
        acc3 += __shfl_xor(acc3, off, 64);
    }

    __shared__ float red[4][4];
    int lane = tid & 63, wv_ = tid >> 6;
    if (lane == 0) {
        red[wv_][0] = acc0; red[wv_][1] = acc1;
        red[wv_][2] = acc2; red[wv_][3] = acc3;
    }
    __syncthreads();
    if (tid < 4) {
        float s = red[0][tid] + red[1][tid] + red[2][tid] + red[3][tid] + bias[k];
        out[tid * 100 + k] = s;
    }
}

// ---------------------------------------------------------------------------
extern "C" void kernel_launch(void* const* d_in, const int* in_sizes, int n_in,
                              void* d_out, int out_size, void* d_ws, size_t ws_size,
                              hipStream_t stream)
{
    const int*   adj  = (const int*)d_in[0];
    const float* emb  = (const float*)d_in[1];
    const float* W    = (const float*)d_in[2];
    const float* a    = (const float*)d_in[3];
    const float* fc1w = (const float*)d_in[4];
    const float* fc1b = (const float*)d_in[5];
    float* out = (float*)d_out;

    float* ws   = (float*)d_ws;
    float* h0G  = ws;               // 4096
    float* h1G  = ws + 4096;        // 4096
    float* h2G  = ws + 8192;        // 4096
    float* dstG = ws + 12288;       // 4096
    float* srcG = ws + 16384;       // 4096
    float* xG   = ws + 20480;       // 4*4096*3 = 49152

    prep_kernel<<<N_ENT / 256, 256, 0, stream>>>(emb, W, a, h0G, h1G, h2G, dstG, srcG);
    gat_row_kernel<<<N_ENT / 16, 1024, 0, stream>>>(adj, h0G, h1G, h2G, dstG, srcG, xG);
    fc_kernel<<<100, 256, 0, stream>>>(xG, fc1w, fc1b, out);
}